// Round 5
// baseline (95.337 us; speedup 1.0000x reference)
//
#include <hip/hip_runtime.h>

// FeatureWithRelativePosition: fused pairwise-dist -> Linear(4096->64) -> LN -> SiLU
// BS=4, N=4096, FEAT=64. fp32 in/out, bf16 MFMA inner product, fp32 accumulate.
//
// R5: 512 blocks x 512 thr (8 waves), 32 rows/block, waves = 8 K-slices, each
//     wave covers all 32 rows (2 rowtiles x 4 ftiles = 8 MFMA per chunk from
//     4 LDS reads). Positions read from a SoA transpose in ws via VMEM (L1),
//     LDS holds only the 2x32KiB W double-buffer -> 2 blocks/CU so barrier
//     drains overlap across blocks. (R4 was 1 block/CU, LDS-pipe+barrier bound.)

typedef float f32x4 __attribute__((ext_vector_type(4)));
typedef __bf16 bf16x8 __attribute__((ext_vector_type(8)));

union BF8 { bf16x8 v; uint4 u; };

#define N_PTS 4096
#define FEATD 64
#define BK 256
#define NCH 16

// ---- prep: blocks 0..127 convert W fp32 -> bf16 granule-major Wbt[512][64][8];
//      blocks 128..143 transpose pos -> Pt[coord][batch][4096] (SoA) ----
__global__ void prep_kernel(const float* __restrict__ W,
                            const float* __restrict__ pos,
                            unsigned short* __restrict__ Wbt,
                            float* __restrict__ Pt) {
  int b = blockIdx.x, t = threadIdx.x;  // 256 threads
  if (b < 128) {
    int gid = b * 256 + t;              // 32768 = 64 f * 512 G
    int f = gid >> 9, m8 = gid & 511;
    const float4* src = (const float4*)(W + (size_t)f * N_PTS + m8 * 8);
    float4 a = src[0], bb = src[1];
    BF8 o;
    o.v[0] = (__bf16)a.x;  o.v[1] = (__bf16)a.y;  o.v[2] = (__bf16)a.z;  o.v[3] = (__bf16)a.w;
    o.v[4] = (__bf16)bb.x; o.v[5] = (__bf16)bb.y; o.v[6] = (__bf16)bb.z; o.v[7] = (__bf16)bb.w;
    ((uint4*)Wbt)[(size_t)m8 * 64 + f] = o.u;
  } else {
    int bb = b - 128;          // 0..15
    int batch = bb >> 2, qtr = bb & 3;
    // quarter = 1024 pts = 768 source float4; 256 dest float4 per coord array
    const float4* p4 = (const float4*)(pos + ((size_t)batch * N_PTS + qtr * 1024) * 3);
    float4 f0 = p4[t * 3 + 0], f1 = p4[t * 3 + 1], f2 = p4[t * 3 + 2];
    float4* Px = (float4*)(Pt + (size_t)(0 * 4 + batch) * N_PTS) + qtr * 256;
    float4* Py = (float4*)(Pt + (size_t)(1 * 4 + batch) * N_PTS) + qtr * 256;
    float4* Pz = (float4*)(Pt + (size_t)(2 * 4 + batch) * N_PTS) + qtr * 256;
    Px[t] = make_float4(f0.x, f0.w, f1.z, f2.y);
    Py[t] = make_float4(f0.y, f1.x, f1.w, f2.z);
    Pz[t] = make_float4(f0.z, f1.y, f2.x, f2.w);
  }
}

__device__ __forceinline__ void load_lds16(const void* g, void* l) {
  __builtin_amdgcn_global_load_lds(
      (const __attribute__((address_space(1))) void*)g,
      (__attribute__((address_space(3))) void*)l, 16, 0, 0);
}

// grid = 512 (batch = bid>>7, rowblk = (bid&127)*32), block = 512 thr (8 waves).
// wave = K-slice (32 k per 256-k chunk); every wave covers all 32 rows.
__global__ __launch_bounds__(512, 4) void frp_kernel(
    const float* __restrict__ pos, const float* __restrict__ W,
    const float* __restrict__ bias, const float* __restrict__ gamma,
    const float* __restrict__ beta, const unsigned short* __restrict__ Wbt,
    const float* __restrict__ Pt, float* __restrict__ out) {
  __shared__ uint4 Wbuf[2][2048];   // 64 KiB total: slot = g*64 + f

  const int tid = threadIdx.x;
  const int lane = tid & 63;
  const int wave = tid >> 6;       // 0..7 = K-slice
  const int fx = lane & 15;
  const int q = lane >> 4;

  const int batch = blockIdx.x >> 7;
  const int rb = (blockIdx.x & 127) * 32;
  const float* posB = pos + (size_t)batch * N_PTS * 3;
  const bool useWs = (Wbt != nullptr);

  const float* PxG = Pt + (size_t)(0 * 4 + batch) * N_PTS;
  const float* PyG = Pt + (size_t)(1 * 4 + batch) * N_PTS;
  const float* PzG = Pt + (size_t)(2 * 4 + batch) * N_PTS;

  // A-row positions (2 rowtiles): rows rb + a*16 + fx
  float px0, py0, pz0, px1, py1, pz1;
  {
    int n0 = rb + fx;
    if (useWs) {
      px0 = PxG[n0];      py0 = PyG[n0];      pz0 = PzG[n0];
      px1 = PxG[n0 + 16]; py1 = PyG[n0 + 16]; pz1 = PzG[n0 + 16];
    } else {
      px0 = posB[n0 * 3];        py0 = posB[n0 * 3 + 1];        pz0 = posB[n0 * 3 + 2];
      px1 = posB[(n0 + 16) * 3]; py1 = posB[(n0 + 16) * 3 + 1]; pz1 = posB[(n0 + 16) * 3 + 2];
    }
  }

  // ---- W chunk staging: 2048 consecutive uint4 (granule-major), 4 per thread ----
  auto stageW = [&](int c, int b) {
#pragma unroll
    for (int it = 0; it < 4; ++it) {
      int gi = it * 512 + tid;
      if (useWs) {
        load_lds16(Wbt + ((size_t)c * 2048 + gi) * 8, &Wbuf[b][gi]);
      } else {
        int g = gi >> 6, f = gi & 63;
        const float4* src = (const float4*)(W + (size_t)f * N_PTS + c * BK + g * 8);
        float4 a = src[0], b2 = src[1];
        BF8 o;
        o.v[0] = (__bf16)a.x;  o.v[1] = (__bf16)a.y;  o.v[2] = (__bf16)a.z;  o.v[3] = (__bf16)a.w;
        o.v[4] = (__bf16)b2.x; o.v[5] = (__bf16)b2.y; o.v[6] = (__bf16)b2.z; o.v[7] = (__bf16)b2.w;
        Wbuf[b][gi] = o.u;
      }
    }
  };

  f32x4 acc[2][4];
#pragma unroll
  for (int a = 0; a < 2; ++a)
#pragma unroll
    for (int t = 0; t < 4; ++t) acc[a][t] = (f32x4){0.f, 0.f, 0.f, 0.f};

  stageW(0, 0);
  __syncthreads();

  const int g8 = wave * 4 + q;     // this lane's granule (8 pts) within each chunk

  for (int c = 0; c < NCH; ++c) {
    if (c + 1 < NCH) stageW(c + 1, (c + 1) & 1);   // DMA next tile (in flight over compute)
    const uint4* Wcur = Wbuf[c & 1];

    // 8 k-points of this lane's granule, via VMEM (SoA in ws, L1-resident)
    float kx[8], ky[8], kz[8];
    if (useWs) {
      const int m4 = c * 64 + g8 * 2;
      f32x4 xa = ((const f32x4*)PxG)[m4], xb = ((const f32x4*)PxG)[m4 + 1];
      f32x4 ya = ((const f32x4*)PyG)[m4], yb = ((const f32x4*)PyG)[m4 + 1];
      f32x4 za = ((const f32x4*)PzG)[m4], zb = ((const f32x4*)PzG)[m4 + 1];
#pragma unroll
      for (int j = 0; j < 4; ++j) {
        kx[j] = xa[j]; ky[j] = ya[j]; kz[j] = za[j];
        kx[4 + j] = xb[j]; ky[4 + j] = yb[j]; kz[4 + j] = zb[j];
      }
    } else {
      const float* pk = posB + ((size_t)c * BK + g8 * 8) * 3;
#pragma unroll
      for (int j = 0; j < 8; ++j) {
        kx[j] = pk[j * 3]; ky[j] = pk[j * 3 + 1]; kz[j] = pk[j * 3 + 2];
      }
    }

    bf16x8 af0, af1;
#pragma unroll
    for (int j = 0; j < 8; ++j) {
      float dx = kx[j] - px0, dy = ky[j] - py0, dz = kz[j] - pz0;
      af0[j] = (__bf16)__builtin_amdgcn_sqrtf(dx * dx + dy * dy + dz * dz);
      dx = kx[j] - px1; dy = ky[j] - py1; dz = kz[j] - pz1;
      af1[j] = (__bf16)__builtin_amdgcn_sqrtf(dx * dx + dy * dy + dz * dz);
    }

#pragma unroll
    for (int t = 0; t < 4; ++t) {
      BF8 bw;
      bw.u = Wcur[g8 * 64 + t * 16 + fx];   // conflict-free (slot%8 == fx%8)
      acc[0][t] = __builtin_amdgcn_mfma_f32_16x16x32_bf16(af0, bw.v, acc[0][t], 0, 0, 0);
      acc[1][t] = __builtin_amdgcn_mfma_f32_16x16x32_bf16(af1, bw.v, acc[1][t], 0, 0, 0);
    }
    __syncthreads();   // next-tile DMA landed during compute; swap buffers
  }

  // ---- 8-way K-merge via LDS tree (reuse Wbuf; region = 512 f32x4 = 8 KiB) ----
  f32x4* mbv = (f32x4*)Wbuf;
  auto wr = [&](int rg) {
#pragma unroll
    for (int a = 0; a < 2; ++a)
#pragma unroll
      for (int t = 0; t < 4; ++t)
        mbv[rg * 512 + (a * 4 + t) * 64 + lane] = acc[a][t];
  };
  auto rd = [&](int rg) {
#pragma unroll
    for (int a = 0; a < 2; ++a)
#pragma unroll
      for (int t = 0; t < 4; ++t)
        acc[a][t] += mbv[rg * 512 + (a * 4 + t) * 64 + lane];
  };
  if (wave >= 4) wr(wave - 4);
  __syncthreads();
  if (wave < 4) rd(wave);
  __syncthreads();
  if (wave == 2 || wave == 3) wr(wave - 2);
  __syncthreads();
  if (wave < 2) rd(wave);
  __syncthreads();
  if (wave == 1) wr(0);
  __syncthreads();

  if (wave == 0) {
    rd(0);
    // epilogue: bias + LayerNorm(64) + SiLU. C/D layout: col=lane&15, row=q*4+r.
    float bb[4], gg[4], be[4];
#pragma unroll
    for (int t = 0; t < 4; ++t) {
      bb[t] = bias[t * 16 + fx];
      gg[t] = gamma[t * 16 + fx];
      be[t] = beta[t * 16 + fx];
    }
    float* outB = out + ((size_t)batch * N_PTS + rb) * FEATD;
#pragma unroll
    for (int a = 0; a < 2; ++a) {
#pragma unroll
      for (int r = 0; r < 4; ++r) {
        float x[4], d[4];
#pragma unroll
        for (int t = 0; t < 4; ++t) x[t] = acc[a][t][r] + bb[t];
        float s = x[0] + x[1] + x[2] + x[3];
        s += __shfl_xor(s, 1); s += __shfl_xor(s, 2);
        s += __shfl_xor(s, 4); s += __shfl_xor(s, 8);
        float mu = s * (1.f / 64.f);
        float v = 0.f;
#pragma unroll
        for (int t = 0; t < 4; ++t) { d[t] = x[t] - mu; v += d[t] * d[t]; }
        v += __shfl_xor(v, 1); v += __shfl_xor(v, 2);
        v += __shfl_xor(v, 4); v += __shfl_xor(v, 8);
        float rstd = __builtin_amdgcn_rsqf(v * (1.f / 64.f) + 1e-5f);
        float* orow = outB + (a * 16 + q * 4 + r) * FEATD;
#pragma unroll
        for (int t = 0; t < 4; ++t) {
          float xn = d[t] * rstd * gg[t] + be[t];
          float y = xn * (1.f / (1.f + __expf(-xn)));  // SiLU
          orow[t * 16 + fx] = y;
        }
      }
    }
  }
}

extern "C" void kernel_launch(void* const* d_in, const int* in_sizes, int n_in,
                              void* d_out, int out_size, void* d_ws, size_t ws_size,
                              hipStream_t stream) {
  const float* pos   = (const float*)d_in[0];  // (4,4096,3)
  const float* W     = (const float*)d_in[1];  // (64,4096)
  const float* bias  = (const float*)d_in[2];  // (64,)
  const float* gamma = (const float*)d_in[3];  // (64,)
  const float* beta  = (const float*)d_in[4];  // (64,)
  float* out = (float*)d_out;                  // (4,4096,64)

  const size_t wb_bytes = (size_t)FEATD * N_PTS * sizeof(unsigned short);  // 512 KiB
  const size_t pt_bytes = (size_t)3 * 4 * N_PTS * sizeof(float);           // 192 KiB
  int use_ws = (d_ws != nullptr && ws_size >= wb_bytes + pt_bytes);
  unsigned short* Wbt = use_ws ? (unsigned short*)d_ws : nullptr;
  float* Pt = use_ws ? (float*)((char*)d_ws + wb_bytes) : nullptr;

  if (use_ws) {
    prep_kernel<<<dim3(144), dim3(256), 0, stream>>>(W, pos, Wbt, Pt);
  }
  frp_kernel<<<dim3(512), dim3(512), 0, stream>>>(pos, W, bias, gamma, beta, Wbt, Pt, out);
}